// Round 3
// baseline (1851.769 us; speedup 1.0000x reference)
//
#include <hip/hip_runtime.h>
#include <cstdint>
#include <cstddef>

#define DI static __device__ __forceinline__

typedef __bf16 bf16x8 __attribute__((ext_vector_type(8)));
typedef float  f32x4  __attribute__((ext_vector_type(4)));

DI ushort f2bf(float f) {
  uint32_t u = __float_as_uint(f);
  uint32_t r = (u + 0x7FFFu + ((u >> 16) & 1u)) >> 16;  // RNE
  return (ushort)r;
}

// ---------------- h0 = latent @ W_dense + b_dense  ([16,512]@[512,1024]) ----------------
__global__ __launch_bounds__(256) void k_dense_h0(const float* __restrict__ latent,
    const float* __restrict__ Wd, const float* __restrict__ bd, float* __restrict__ h0) {
  int b = blockIdx.x >> 2;
  int u = ((blockIdx.x & 3) << 8) + threadIdx.x;
  const float* lrow = latent + (b << 9);
  float acc = bd[u];
  #pragma unroll 8
  for (int k = 0; k < 512; ++k) acc = fmaf(lrow[k], Wd[((size_t)k << 10) + u], acc);
  h0[(b << 10) + u] = acc;
}

// ---------------- transpose [R][C] f32 -> [C][R] f32 or bf16 ----------------
template<typename OutT>
__global__ __launch_bounds__(256) void k_transpose(const float* __restrict__ src,
    OutT* __restrict__ dst, int R, int C) {
  __shared__ float tile[32][33];
  int c0 = blockIdx.x << 5, r0 = blockIdx.y << 5;
  int tx = threadIdx.x, ty = threadIdx.y;
  #pragma unroll
  for (int i = 0; i < 32; i += 8)
    tile[ty + i][tx] = src[(size_t)(r0 + ty + i) * C + (c0 + tx)];
  __syncthreads();
  #pragma unroll
  for (int i = 0; i < 32; i += 8) {
    float v = tile[tx][ty + i];
    size_t o = (size_t)(c0 + ty + i) * R + (r0 + tx);
    if constexpr (sizeof(OutT) == 2) dst[o] = f2bf(v); else dst[o] = v;
  }
}

// ---------------- gather emb[teacher] -> bf16 [2048][512] (rows >=2032 zero) ----------------
__global__ __launch_bounds__(256) void k_gather_x(const float* __restrict__ emb,
    const int* __restrict__ tok, ushort* __restrict__ xb) {
  int gid = (blockIdx.x << 8) + threadIdx.x;        // 2048*128 float4 chunks
  int m = gid >> 7, k4 = gid & 127;
  float4 v = make_float4(0.f, 0.f, 0.f, 0.f);
  if (m < 2032) {
    int b = m / 127, t = m - b * 127;
    int token = tok[(b << 7) + t];
    v = ((const float4*)(emb + ((size_t)token << 9)))[k4];
  }
  ushort4 o; o.x = f2bf(v.x); o.y = f2bf(v.y); o.z = f2bf(v.z); o.w = f2bf(v.w);
  ((ushort4*)xb)[gid] = o;
}

// ---------------- zero pad rows 2032..2047 of hsb ----------------
__global__ __launch_bounds__(256) void k_pad_hsb(ushort* __restrict__ hsb) {
  int row = 2032 + blockIdx.x;
  ushort4 z; z.x = 0; z.y = 0; z.z = 0; z.w = 0;
  ((ushort4*)(hsb + ((size_t)row << 10)))[threadIdx.x] = z;
}

// ---------------- GRU step (fp32), 4-way K-split ----------------
// grid 256 (4 u each), block 256 = 16 b x 4 u x 4 kq (kq = wave). WhT is [3072][1024] f32.
__global__ __launch_bounds__(256) void k_gru_step(const float* __restrict__ h_cur,
    float* __restrict__ h_next, ushort* __restrict__ hsb, const float* __restrict__ xp,
    const float* __restrict__ WhT, const float* __restrict__ b_h,
    const int* __restrict__ tok, int t) {
  __shared__ __attribute__((aligned(16))) float hs[4 * 16 * 260];  // per-wave h quarter
  __shared__ float red[3][260];
  int tid = threadIdx.x;
  int lane = tid & 63, kq = tid >> 6;
  int b = tid & 15, ul = (tid >> 4) & 3;
  int u = (blockIdx.x << 2) + ul;
  int m = b * 127 + t;

  // prefetch finish-phase scalars (wave 0 only; hides L2 latency under the k-loop)
  float xz = 0.f, xr = 0.f, xh = 0.f, bz = 0.f, br = 0.f, bhh = 0.f, hprev = 0.f;
  int tk = 1;
  if (kq == 0) {
    const float* xrow = xp + (size_t)m * 3072;
    xz = xrow[u]; xr = xrow[1024 + u]; xh = xrow[2048 + u];
    bz = b_h[u]; br = b_h[1024 + u]; bhh = b_h[2048 + u];
    hprev = h_cur[(b << 10) + u];
    tk = tok[(b << 7) + t];
  }

  // stage this wave's h quarter: h[0:16][kq*256 .. +256) -> LDS rows of 64 float4 (stride 260 f32)
  float* hw = hs + kq * (16 * 260);
  const float4* hv = (const float4*)h_cur;   // h row = 256 float4
  #pragma unroll
  for (int i = 0; i < 16; ++i) {
    int idx = (i << 6) + lane;               // 0..1023 over [16 b][64 float4]
    int bb = idx >> 6, kk = idx & 63;
    ((float4*)(hw + bb * 260))[kk] = hv[(bb << 8) + (kq << 6) + kk];
  }
  __syncthreads();

  const float4* h4 = (const float4*)(hw + b * 260);
  const float4* wz = (const float4*)(WhT + ((size_t)u << 10)) + (kq << 6);
  const float4* wr = (const float4*)(WhT + ((size_t)(1024 + u) << 10)) + (kq << 6);
  const float4* wh = (const float4*)(WhT + ((size_t)(2048 + u) << 10)) + (kq << 6);
  float az = 0.f, ar = 0.f, ah = 0.f;
  #pragma unroll 8
  for (int k = 0; k < 64; ++k) {
    float4 h = h4[k];
    float4 a = wz[k], e = wr[k], c = wh[k];
    az = fmaf(h.x, a.x, fmaf(h.y, a.y, fmaf(h.z, a.z, fmaf(h.w, a.w, az))));
    ar = fmaf(h.x, e.x, fmaf(h.y, e.y, fmaf(h.z, e.z, fmaf(h.w, e.w, ar))));
    ah = fmaf(h.x, c.x, fmaf(h.y, c.y, fmaf(h.z, c.z, fmaf(h.w, c.w, ah))));
  }
  red[0][tid] = az; red[1][tid] = ar; red[2][tid] = ah;
  __syncthreads();

  if (tid < 64) {                            // kq==0 threads finish (same b,ul mapping)
    az = red[0][tid] + red[0][tid + 64] + red[0][tid + 128] + red[0][tid + 192];
    ar = red[1][tid] + red[1][tid + 64] + red[1][tid + 128] + red[1][tid + 192];
    ah = red[2][tid] + red[2][tid + 64] + red[2][tid + 128] + red[2][tid + 192];
    float z = 1.f / (1.f + __expf(-(xz + az + bz)));
    float r = 1.f / (1.f + __expf(-(xr + ar + br)));
    float hc = tanhf(xh + r * (ah + bhh));
    float hn = z * hprev + (1.f - z) * hc;
    if (tk == 0) hn = hprev;
    h_next[(b << 10) + u] = hn;
    hsb[((size_t)m << 10) + u] = f2bf(hn);
  }
}

// ---------------- bf16 MFMA GEMM: C[Mreal,N] = A[M,K] @ BT[N,K]^T + bias ----------------
// 128x128 tile, BK=64, 4 waves, global_load_lds(16B) staging, XOR-swizzled LDS.
// Tile order: m-fastest within XCD-chunked swizzle (gridDim.x % 8 == 0 required).
__global__ __launch_bounds__(256) void k_gemm_bf16(const ushort* __restrict__ A,
    const ushort* __restrict__ BT, const float* __restrict__ bias, float* __restrict__ C,
    int M, int N, int K, int Mreal, int MT) {
  __shared__ __attribute__((aligned(16))) ushort ldsA[128 * 64];
  __shared__ __attribute__((aligned(16))) ushort ldsB[128 * 64];
  int nwg = gridDim.x;
  int q = nwg >> 3;                               // nwg % 8 == 0
  int swz = (blockIdx.x & 7) * q + (blockIdx.x >> 3);
  int m0 = (swz % MT) << 7;
  int n0 = (swz / MT) << 7;
  int tid = threadIdx.x;
  int lane = tid & 63, wave = tid >> 6;
  int wm = (wave >> 1) << 6, wn = (wave & 1) << 6;
  f32x4 acc[4][4] = {};
  const char* Ab = (const char*)A;
  const char* Bb = (const char*)BT;
  size_t stride = (size_t)K * 2;  // bytes per row

  for (int k0 = 0; k0 < K; k0 += 64) {
    #pragma unroll
    for (int it = 0; it < 4; ++it) {
      int c = (it << 8) + tid;                   // chunk 0..1023 (16B each)
      int row = c >> 3;
      int cb = ((c & 7) << 4) ^ ((row & 7) << 4);  // pre-swizzled source column
      const char* ga = Ab + (size_t)(m0 + row) * stride + (size_t)(k0 << 1) + cb;
      const char* gb = Bb + (size_t)(n0 + row) * stride + (size_t)(k0 << 1) + cb;
      // wave-uniform LDS base; HW adds lane*16
      __builtin_amdgcn_global_load_lds((const __attribute__((address_space(1))) void*)ga,
          (__attribute__((address_space(3))) void*)(ldsA + (((it << 2) + wave) << 9)), 16, 0, 0);
      __builtin_amdgcn_global_load_lds((const __attribute__((address_space(1))) void*)gb,
          (__attribute__((address_space(3))) void*)(ldsB + (((it << 2) + wave) << 9)), 16, 0, 0);
    }
    __syncthreads();
    #pragma unroll
    for (int kk = 0; kk < 2; ++kk) {
      bf16x8 av[4], bv[4];
      int kb = (kk << 6) + ((lane >> 4) << 4);   // byte offset of 8 bf16 along K
      #pragma unroll
      for (int f = 0; f < 4; ++f) {
        int ra = wm + (f << 4) + (lane & 15);
        av[f] = *(const bf16x8*)((const char*)ldsA + ra * 128 + (kb ^ ((ra & 7) << 4)));
        int rb = wn + (f << 4) + (lane & 15);
        bv[f] = *(const bf16x8*)((const char*)ldsB + rb * 128 + (kb ^ ((rb & 7) << 4)));
      }
      #pragma unroll
      for (int fm = 0; fm < 4; ++fm)
        #pragma unroll
        for (int fn = 0; fn < 4; ++fn)
          acc[fm][fn] = __builtin_amdgcn_mfma_f32_16x16x32_bf16(av[fm], bv[fn], acc[fm][fn], 0, 0, 0);
    }
    __syncthreads();
  }

  #pragma unroll
  for (int fn = 0; fn < 4; ++fn) {
    int n = n0 + wn + (fn << 4) + (lane & 15);
    float bvs = bias ? bias[n] : 0.f;
    #pragma unroll
    for (int fm = 0; fm < 4; ++fm) {
      int mbase = m0 + wm + (fm << 4) + ((lane >> 4) << 2);
      #pragma unroll
      for (int r = 0; r < 4; ++r) {
        int m = mbase + r;
        if (m < Mreal) C[(size_t)m * N + n] = acc[fm][fn][r] + bvs;
      }
    }
  }
}

extern "C" void kernel_launch(void* const* d_in, const int* in_sizes, int n_in,
                              void* d_out, int out_size, void* d_ws, size_t ws_size,
                              hipStream_t stream) {
  (void)in_sizes; (void)n_in; (void)out_size; (void)ws_size;
  const float* latent = (const float*)d_in[0];
  const int*   tok    = (const int*)d_in[1];
  const float* emb    = (const float*)d_in[2];
  const float* Wd     = (const float*)d_in[3];
  const float* bd     = (const float*)d_in[4];
  const float* Wx     = (const float*)d_in[5];
  const float* Wh     = (const float*)d_in[6];
  const float* bx     = (const float*)d_in[7];
  const float* bh     = (const float*)d_in[8];
  const float* Wout   = (const float*)d_in[9];
  const float* bout   = (const float*)d_in[10];
  float* out = (float*)d_out;

  char* w = (char*)d_ws;
  float*  h0v = (float*)(w + 0);            // [16][1024] f32
  float*  h1v = (float*)(w + 65536);        // [16][1024] f32
  float*  WhT = (float*)(w + 131072);       // [3072][1024] f32
  float*  xp  = (float*)(w + 12713984);     // [2032][3072] f32
  ushort* xb  = (ushort*)(w + 37683200);    // [2048][512] bf16
  ushort* WxT = (ushort*)(w + 39780352);    // [3072][512] bf16
  ushort* hsb = (ushort*)(w + 42926080);    // [2048][1024] bf16
  ushort* WoT = (ushort*)(w + 47120384);    // [32000][1024] bf16
  // total ws usage: 112656384 bytes (~107.5 MB)

  // weight preprocessing
  k_transpose<float ><<<dim3(96, 32),   dim3(32, 8), 0, stream>>>(Wh,   WhT, 1024, 3072);
  k_transpose<ushort><<<dim3(96, 16),   dim3(32, 8), 0, stream>>>(Wx,   WxT,  512, 3072);
  k_transpose<ushort><<<dim3(1000, 32), dim3(32, 8), 0, stream>>>(Wout, WoT, 1024, 32000);

  // h0, embedded inputs, hsb pad rows
  k_dense_h0<<<64, 256, 0, stream>>>(latent, Wd, bd, h0v);
  k_gather_x<<<1024, 256, 0, stream>>>(emb, tok, xb);
  k_pad_hsb<<<16, 256, 0, stream>>>(hsb);

  // xp = x @ W_x + b_x   (M=2048 padded -> 16 m-tiles, N=3072 -> 24 n-tiles)
  k_gemm_bf16<<<384, 256, 0, stream>>>(xb, WxT, bx, xp, 2048, 3072, 512, 2032, 16);

  // sequential GRU scan (127 steps), writes hsb bf16 directly
  float* hc = h0v; float* hn = h1v;
  for (int t = 0; t < 127; ++t) {
    k_gru_step<<<256, 256, 0, stream>>>(hc, hn, hsb, xp, WhT, bh, tok, t);
    float* tmp = hc; hc = hn; hn = tmp;
  }

  // logits = hseq @ W_out + b_out  (M=2048 -> 16 m-tiles, N=32000 -> 250 n-tiles)
  k_gemm_bf16<<<4000, 256, 0, stream>>>(hsb, WoT, bout, out, 2048, 32000, 1024, 2032, 16);
}